// Round 11
// baseline (288.291 us; speedup 1.0000x reference)
//
#include <hip/hip_runtime.h>
#include <stdint.h>

// HeAttention, MI355X/gfx950 — Round 11: single persistent kernel, high-TLP
// stage-free phases + R7-proven grid barriers.
//   Phase 1 proj: 448 tiles x 4 quadrants = 1792 wave-tasks (stage-free,
//     no barriers, 8 waves/CU).
//   Phase 2 attn: R8/R9 body (scores + softmax + PV), per-wave LDS regions.
//   Phase 3 out: 64 tiles x 4 quadrants = 256 wave-tasks, stage-free.
// LDS 109.6 KB -> 1 block/CU; 256 blocks <= 256 CUs co-resident => spin
// barrier safe (validated R7). fp32 I/O, bf16 MFMA internally.
// B=1, S=512, D=512, H=8, hd=64, NE=1024.

typedef __bf16 bf16_t;
typedef bf16_t bf16x8 __attribute__((ext_vector_type(8)));
typedef float f32x4 __attribute__((ext_vector_type(4)));
typedef float f32x2v __attribute__((ext_vector_type(2)));
typedef bf16_t bf16x2v __attribute__((ext_vector_type(2)));

__device__ __forceinline__ uint16_t f2bf(float f) {
  bf16_t b = (bf16_t)f;                       // compiler RNE (HW cvt)
  union { bf16_t b; uint16_t u; } c; c.b = b; return c.u;
}
__device__ __forceinline__ uint32_t cvt2(float lo, float hi) {
  bf16x2v v = __builtin_convertvector((f32x2v){lo, hi}, bf16x2v);
  union { bf16x2v v; uint32_t u; } c; c.v = v; return c.u;
}
__device__ __forceinline__ bf16x8 cvt8f(float4 a, float4 b) {
  uint4 r;
  r.x = cvt2(a.x, a.y); r.y = cvt2(a.z, a.w);
  r.z = cvt2(b.x, b.y); r.w = cvt2(b.z, b.w);
  union { uint4 u; bf16x8 v; } c; c.u = r; return c.v;
}
#define MFMA(a, b, c) __builtin_amdgcn_mfma_f32_16x16x32_bf16((a), (b), (c), 0, 0, 0)

#define SSTR 72     // P-tile stride (bf16)
#define RGN  13568  // attn per-wave LDS region bytes
#define NBLK 256
#define BAR_MAGIC 0x1357A5A5

__device__ __forceinline__ void grid_bar(int* bar, int idx) {
  __syncthreads();
  if (threadIdx.x == 0) {
    __threadfence();  // release
    while (__hip_atomic_load(&bar[2], __ATOMIC_ACQUIRE, __HIP_MEMORY_SCOPE_AGENT) != BAR_MAGIC)
      __builtin_amdgcn_s_sleep(1);
    __hip_atomic_fetch_add(&bar[idx], 1, __ATOMIC_ACQ_REL, __HIP_MEMORY_SCOPE_AGENT);
    while (__hip_atomic_load(&bar[idx], __ATOMIC_ACQUIRE, __HIP_MEMORY_SCOPE_AGENT) < NBLK)
      __builtin_amdgcn_s_sleep(1);
    __threadfence();  // acquire
  }
  __syncthreads();
  __threadfence();
}

__global__ __launch_bounds__(512, 2) void fused_kernel(
    const float* __restrict__ X, const float* __restrict__ emb,
    const float* __restrict__ wq, const float* __restrict__ bq,
    const float* __restrict__ wk, const float* __restrict__ bk,
    const float* __restrict__ wv, const float* __restrict__ bv,
    const float* __restrict__ wrk, const float* __restrict__ brk,
    const float* __restrict__ wrq, const float* __restrict__ brq,
    const float* __restrict__ wo, const float* __restrict__ bo,
    uint16_t* __restrict__ q, uint16_t* __restrict__ k, uint16_t* __restrict__ vT,
    uint16_t* __restrict__ rkE, uint16_t* __restrict__ rqE,
    uint16_t* __restrict__ ctx_bf, float* __restrict__ attn,
    float* __restrict__ outp, int* __restrict__ bar)
{
  __shared__ __align__(16) char smem[8 * RGN + 1024];   // 109568 B -> 1 blk/CU
  const int bid = blockIdx.x;
  const int t = threadIdx.x, lane = t & 63, w = t >> 6;
  const int quad = lane >> 4, l15 = lane & 15;

  if (bid == 0 && t == 0) {
    __hip_atomic_store(&bar[0], 0, __ATOMIC_RELAXED, __HIP_MEMORY_SCOPE_AGENT);
    __hip_atomic_store(&bar[1], 0, __ATOMIC_RELAXED, __HIP_MEMORY_SCOPE_AGENT);
    __hip_atomic_store(&bar[2], BAR_MAGIC, __ATOMIC_RELEASE, __HIP_MEMORY_SCOPE_AGENT);
  }

  // ========== Phase 1: projections, stage-free quadrant wave-tasks ==========
  // task gw in [0,1792): tile v = gw>>2, quadrant qd = gw&3 (32x32).
  {
    const int gw = bid * 8 + w;
    if (gw < 1792) {
      int v = gw >> 2; const int qd = gw & 3;
      const float *A, *B, *bias; uint16_t* C; int mode;
      if (v < 64)       {           A = X;   B = wq;  bias = bq;  C = q;   mode = 2; }
      else if (v < 128) { v -= 64;  A = X;   B = wk;  bias = bk;  C = k;   mode = 2; }
      else if (v < 192) { v -= 128; A = X;   B = wv;  bias = bv;  C = vT;  mode = 3; }
      else if (v < 320) { v -= 192; A = emb; B = wrk; bias = brk; C = rkE; mode = 1; }
      else              { v -= 320; A = emb; B = wrq; bias = brq; C = rqE; mode = 1; }
      const int m0 = (v >> 3) * 64 + (qd & 1) * 32;
      const int n0 = (v & 7) * 64 + (qd >> 1) * 32;

      const float* Ab = A + (size_t)(m0 + l15) * 512 + quad * 8;
      const float* Bb = B + (size_t)(n0 + l15) * 512 + quad * 8;

      f32x4 acc[2][2] = {};
      for (int k0 = 0; k0 < 512; k0 += 32) {
        bf16x8 af[2], bfr[2];
#pragma unroll
        for (int x = 0; x < 2; x++) {
          const float* pa = Ab + (size_t)(x * 16) * 512 + k0;
          af[x] = cvt8f(*(const float4*)pa, *(const float4*)(pa + 4));
        }
#pragma unroll
        for (int y = 0; y < 2; y++) {
          const float* pb = Bb + (size_t)(y * 16) * 512 + k0;
          bfr[y] = cvt8f(*(const float4*)pb, *(const float4*)(pb + 4));
        }
#pragma unroll
        for (int x = 0; x < 2; x++)
#pragma unroll
          for (int y = 0; y < 2; y++)
            acc[x][y] = MFMA(af[x], bfr[y], acc[x][y]);
      }
#pragma unroll
      for (int x = 0; x < 2; x++)
#pragma unroll
        for (int y = 0; y < 2; y++) {
          const int j = n0 + y * 16 + l15;
          const float bval = bias[j];
          const int ib = m0 + x * 16 + quad * 4;
#pragma unroll
          for (int r = 0; r < 4; r++) {
            const int i = ib + r;
            size_t off;
            if (mode == 1)      off = (size_t)i * 512 + j;
            else if (mode == 2) off = (size_t)(j >> 6) * 32768 + (size_t)i * 64 + (size_t)(j & 63);
            else                off = (size_t)(j >> 6) * 32768 + (size_t)(j & 63) * 512 + (size_t)i;
            C[off] = f2bf(acc[x][y][r] + bval);
          }
        }
    }
  }
  grid_bar(bar, 0);

  // ========== Phase 2: attn (scores + softmax + PV), R8/R9 body ==========
  {
    const int h = bid & 7, i0 = (bid >> 3) * 16;   // h == XCD id
    const int j0 = w * 64;
    const int ebase = j0 - i0 + 497;               // in [1, 945]

    char* rgn = smem + w * RGN;
    _Float16* U2h = (_Float16*)rgn;                // 16 x 84
    _Float16* U3h = (_Float16*)(rgn + 2688);       // 80 x 68
    uint16_t* Pw  = (uint16_t*)rgn;                // 16 x SSTR (PV phase)
    float*    ctxw = (float*)(rgn + 4096);         // 16 x 64   (epilogue)
    float* rmax = (float*)(smem + 8 * RGN);        // [8][16]
    float* rsum = rmax + 128;                      // [8][16]

    const uint16_t* qh = q  + (size_t)h * 32768;
    const uint16_t* kh = k  + (size_t)h * 32768;
    const uint16_t* vh = vT + (size_t)h * 32768;

    f32x4 acc1[4] = {}, acc2[5] = {}, acc3[5][4] = {};
#pragma unroll
    for (int s = 0; s < 2; s++) {
      const int ko = s * 32 + quad * 8;
      bf16x8 aq = *(const bf16x8*)(qh + (size_t)(i0 + l15) * 64 + ko);
      bf16x8 bk[4], arq[5], brk[5];
#pragma unroll
      for (int tt = 0; tt < 4; tt++)
        bk[tt] = *(const bf16x8*)(kh + (size_t)(j0 + tt * 16 + l15) * 64 + ko);
#pragma unroll
      for (int x = 0; x < 5; x++) {
        const int e = min(ebase + x * 16 + l15, 1023);
        arq[x] = *(const bf16x8*)(rqE + (size_t)e * 512 + h * 64 + ko);
        brk[x] = *(const bf16x8*)(rkE + (size_t)e * 512 + h * 64 + ko);
      }
#pragma unroll
      for (int tt = 0; tt < 4; tt++) acc1[tt] = MFMA(aq, bk[tt], acc1[tt]);
#pragma unroll
      for (int x = 0; x < 5; x++)    acc2[x] = MFMA(aq, brk[x], acc2[x]);
#pragma unroll
      for (int x = 0; x < 5; x++)
#pragma unroll
        for (int tt = 0; tt < 4; tt++) acc3[x][tt] = MFMA(arq[x], bk[tt], acc3[x][tt]);
    }
    // U round-trip (wave-private, fp16)
#pragma unroll
    for (int x = 0; x < 5; x++)
#pragma unroll
      for (int r = 0; r < 4; r++)
        U2h[(quad * 4 + r) * 84 + x * 16 + l15] = (_Float16)acc2[x][r];
#pragma unroll
    for (int x = 0; x < 5; x++)
#pragma unroll
      for (int tt = 0; tt < 4; tt++)
#pragma unroll
        for (int r = 0; r < 4; r++)
          U3h[(x * 16 + quad * 4 + r) * 68 + tt * 16 + l15] = (_Float16)acc3[x][tt][r];
    __syncthreads();

    f32x4 sc[4];
#pragma unroll
    for (int tt = 0; tt < 4; tt++)
#pragma unroll
      for (int r = 0; r < 4; r++) {
        const int ii = quad * 4 + r, jj = tt * 16 + l15;
        const int rb = jj - ii + 15;   // [0,78]
        sc[tt][r] = (acc1[tt][r] + (float)U2h[ii * 84 + rb] + (float)U3h[rb * 68 + jj]) * 0.125f;
      }

    // softmax over j=512 (8 waves share each row)
    float mrow[4];
#pragma unroll
    for (int r = 0; r < 4; r++) {
      float m = fmaxf(fmaxf(sc[0][r], sc[1][r]), fmaxf(sc[2][r], sc[3][r]));
#pragma unroll
      for (int o = 1; o < 16; o <<= 1) m = fmaxf(m, __shfl_xor(m, o, 64));
      mrow[r] = m;
    }
    if (l15 == 0)
#pragma unroll
      for (int r = 0; r < 4; r++) rmax[w * 16 + quad * 4 + r] = mrow[r];
    __syncthreads();
    float srow[4];
#pragma unroll
    for (int r = 0; r < 4; r++) {
      const int row = quad * 4 + r;
      float m = rmax[row];
#pragma unroll
      for (int x = 1; x < 8; x++) m = fmaxf(m, rmax[x * 16 + row]);
      float s = 0.f;
#pragma unroll
      for (int tt = 0; tt < 4; tt++) {
        const float p = __expf(sc[tt][r] - m);
        sc[tt][r] = p; s += p;
      }
#pragma unroll
      for (int o = 1; o < 16; o <<= 1) s += __shfl_xor(s, o, 64);
      srow[r] = s;
    }
    if (l15 == 0)
#pragma unroll
      for (int r = 0; r < 4; r++) rsum[w * 16 + quad * 4 + r] = srow[r];
    __syncthreads();
#pragma unroll
    for (int r = 0; r < 4; r++) {
      const int row = quad * 4 + r;
      float s = rsum[row];
#pragma unroll
      for (int x = 1; x < 8; x++) s += rsum[x * 16 + row];
      const float inv = 1.0f / s;
#pragma unroll
      for (int tt = 0; tt < 4; tt++) {
        sc[tt][r] *= inv;
        attn[((size_t)h * 512 + i0 + row) * 512 + j0 + tt * 16 + l15] = sc[tt][r];
      }
    }

    // PV: wave-partial ctx[16][64] over this wave's 64 j
#pragma unroll
    for (int tt = 0; tt < 4; tt++)
#pragma unroll
      for (int r = 0; r < 4; r++)
        Pw[(quad * 4 + r) * SSTR + tt * 16 + l15] = f2bf(sc[tt][r]);
    __syncthreads();
    f32x4 apv[4] = {};
#pragma unroll
    for (int s = 0; s < 2; s++) {
      const int ko = s * 32 + quad * 8;
      bf16x8 aP = *(const bf16x8*)(&Pw[l15 * SSTR + ko]);
#pragma unroll
      for (int tt = 0; tt < 4; tt++) {
        bf16x8 bv = *(const bf16x8*)(vh + (size_t)(tt * 16 + l15) * 512 + j0 + ko);
        apv[tt] = MFMA(aP, bv, apv[tt]);
      }
    }
#pragma unroll
    for (int tt = 0; tt < 4; tt++)
#pragma unroll
      for (int r = 0; r < 4; r++)
        ctxw[(quad * 4 + r) * 64 + tt * 16 + l15] = apv[tt][r];
    __syncthreads();
    // cross-wave ctx sum (512 thr x 2 floats) -> ctx_bf
    {
      const int idx = t * 2, row = idx >> 6, col = idx & 63;
      const size_t off = 4096 + (size_t)(row * 64 + col) * 4;
      float c0 = 0.f, c1 = 0.f;
#pragma unroll
      for (int x = 0; x < 8; x++) {
        float2 vv = *(const float2*)(smem + x * RGN + off);
        c0 += vv.x; c1 += vv.y;
      }
      *(uint32_t*)(ctx_bf + (size_t)(i0 + row) * 512 + h * 64 + col) = cvt2(c0, c1);
    }
  }
  grid_bar(bar, 1);

  // ========== Phase 3: out = ctx * wo^T + bo, stage-free quadrants ==========
  // 64 tiles x 4 quadrants = 256 wave-tasks.
  {
    const int gw = bid * 8 + w;
    if (gw < 256) {
      const int v = gw >> 2, qd = gw & 3;
      const int m0 = (v >> 3) * 64 + (qd & 1) * 32;
      const int n0 = (v & 7) * 64 + (qd >> 1) * 32;

      const uint16_t* Ab = ctx_bf + (size_t)(m0 + l15) * 512 + quad * 8;
      const float* Bb = wo + (size_t)(n0 + l15) * 512 + quad * 8;

      f32x4 acc[2][2] = {};
      for (int k0 = 0; k0 < 512; k0 += 32) {
        bf16x8 af[2], bfr[2];
#pragma unroll
        for (int x = 0; x < 2; x++)
          af[x] = *(const bf16x8*)(Ab + (size_t)(x * 16) * 512 + k0);
#pragma unroll
        for (int y = 0; y < 2; y++) {
          const float* pb = Bb + (size_t)(y * 16) * 512 + k0;
          bfr[y] = cvt8f(*(const float4*)pb, *(const float4*)(pb + 4));
        }
#pragma unroll
        for (int x = 0; x < 2; x++)
#pragma unroll
          for (int y = 0; y < 2; y++)
            acc[x][y] = MFMA(af[x], bfr[y], acc[x][y]);
      }
#pragma unroll
      for (int x = 0; x < 2; x++)
#pragma unroll
        for (int y = 0; y < 2; y++) {
          const int j = n0 + y * 16 + l15;
          const float bval = bo[j];
          const int ib = m0 + x * 16 + quad * 4;
#pragma unroll
          for (int r = 0; r < 4; r++)
            outp[(size_t)(ib + r) * 512 + j] = acc[x][y][r] + bval;
        }
    }
  }
}

extern "C" void kernel_launch(void* const* d_in, const int* in_sizes, int n_in,
                              void* d_out, int out_size, void* d_ws, size_t ws_size,
                              hipStream_t stream) {
  const float* X   = (const float*)d_in[0];
  const float* emb = (const float*)d_in[1];
  const float* wq  = (const float*)d_in[2];
  const float* bq  = (const float*)d_in[3];
  const float* wk  = (const float*)d_in[4];
  const float* bk  = (const float*)d_in[5];
  const float* wv  = (const float*)d_in[6];
  const float* bv  = (const float*)d_in[7];
  const float* wrk = (const float*)d_in[8];
  const float* brk = (const float*)d_in[9];
  const float* wrq = (const float*)d_in[10];
  const float* brq = (const float*)d_in[11];
  const float* wo  = (const float*)d_in[12];
  const float* bo  = (const float*)d_in[13];

  // ws layout (uint16 elems, ~4.2 MB): tensors + barrier ints
  uint16_t* q      = (uint16_t*)d_ws;         // [8][512][64]
  uint16_t* k      = q   + 262144;            // [8][512][64]
  uint16_t* vT     = k   + 262144;            // [8][64][512]
  uint16_t* rkE    = vT  + 262144;            // [1024][512]
  uint16_t* rqE    = rkE + 524288;            // [1024][512]
  uint16_t* ctx_bf = rqE + 524288;            // [512][512]
  int*      bar    = (int*)(ctx_bf + 262144); // [3]

  float* outp = (float*)d_out;                // [512][512]
  float* attn = (float*)d_out + 262144;       // [8][512][512]

  fused_kernel<<<dim3(NBLK), dim3(512), 0, stream>>>(
      X, emb, wq, bq, wk, bk, wv, bv, wrk, brk, wrq, brq, wo, bo,
      q, k, vT, rkE, rqE, ctx_bf, attn, outp, bar);
}

// Round 12
// 280.357 us; speedup vs baseline: 1.0283x; 1.0283x over previous
//
#include <hip/hip_runtime.h>
#include <stdint.h>

// HeAttention, MI355X/gfx950 — Round 12: persistent kernel with STORE/SCAN
// grid barrier (R11's atomic-RMW barrier serialized ~75us/barrier; this one
// is per-block flag stores + wave-0 scan, ~3us).
//   Phase 1 proj: 448 tiles x 4 quadrants = 1792 stage-free wave-tasks.
//   Phase 2 attn: R8/R9 body (scores + softmax + PV), per-wave LDS regions.
//   Phase 3 out: 64 tiles x 4 quadrants = 256 stage-free wave-tasks.
// LDS 109.6 KB -> 1 block/CU; 256 blocks <= 256 CUs co-resident (validated
// R7/R11 - no hang). Flags arrays live in ws (0xAA-poisoned each launch, so
// poison != 1 makes them self-initializing; two arrays avoid sense-reversal).
// fp32 I/O, bf16 MFMA internally. B=1, S=512, D=512, H=8, hd=64, NE=1024.

typedef __bf16 bf16_t;
typedef bf16_t bf16x8 __attribute__((ext_vector_type(8)));
typedef float f32x4 __attribute__((ext_vector_type(4)));
typedef float f32x2v __attribute__((ext_vector_type(2)));
typedef bf16_t bf16x2v __attribute__((ext_vector_type(2)));

__device__ __forceinline__ uint16_t f2bf(float f) {
  bf16_t b = (bf16_t)f;                       // compiler RNE (HW cvt)
  union { bf16_t b; uint16_t u; } c; c.b = b; return c.u;
}
__device__ __forceinline__ uint32_t cvt2(float lo, float hi) {
  bf16x2v v = __builtin_convertvector((f32x2v){lo, hi}, bf16x2v);
  union { bf16x2v v; uint32_t u; } c; c.v = v; return c.u;
}
__device__ __forceinline__ bf16x8 cvt8f(float4 a, float4 b) {
  uint4 r;
  r.x = cvt2(a.x, a.y); r.y = cvt2(a.z, a.w);
  r.z = cvt2(b.x, b.y); r.w = cvt2(b.z, b.w);
  union { uint4 u; bf16x8 v; } c; c.u = r; return c.v;
}
#define MFMA(a, b, c) __builtin_amdgcn_mfma_f32_16x16x32_bf16((a), (b), (c), 0, 0, 0)

#define SSTR 72     // P-tile stride (bf16)
#define RGN  13568  // attn per-wave LDS region bytes
#define NBLK 256

// Store/scan grid barrier: block arrival = ONE plain device-scope store to
// its own slot (no RMW serialization); wave 0 scans all 256 flags (4/lane).
__device__ __forceinline__ void grid_bar(int* flags) {
  __syncthreads();
  if (threadIdx.x == 0) {
    __threadfence();  // release: drain this block's stores to device scope
    __hip_atomic_store(&flags[blockIdx.x], 1, __ATOMIC_RELEASE, __HIP_MEMORY_SCOPE_AGENT);
  }
  if (threadIdx.x < 64) {
    const int l = threadIdx.x;
    bool done;
    do {
      bool ok = true;
#pragma unroll
      for (int c = 0; c < 4; c++)
        ok &= (__hip_atomic_load(&flags[c * 64 + l], __ATOMIC_ACQUIRE,
                                 __HIP_MEMORY_SCOPE_AGENT) == 1);
      done = __all(ok);
      if (!done) __builtin_amdgcn_s_sleep(8);
    } while (!done);
  }
  __syncthreads();
  __threadfence();  // acquire: invalidate caches before consuming remote data
}

__global__ __launch_bounds__(512, 2) void fused_kernel(
    const float* __restrict__ X, const float* __restrict__ emb,
    const float* __restrict__ wq, const float* __restrict__ bq,
    const float* __restrict__ wk, const float* __restrict__ bk,
    const float* __restrict__ wv, const float* __restrict__ bv,
    const float* __restrict__ wrk, const float* __restrict__ brk,
    const float* __restrict__ wrq, const float* __restrict__ brq,
    const float* __restrict__ wo, const float* __restrict__ bo,
    uint16_t* __restrict__ q, uint16_t* __restrict__ k, uint16_t* __restrict__ vT,
    uint16_t* __restrict__ rkE, uint16_t* __restrict__ rqE,
    uint16_t* __restrict__ ctx_bf, float* __restrict__ attn,
    float* __restrict__ outp, int* __restrict__ flagsA, int* __restrict__ flagsB)
{
  __shared__ __align__(16) char smem[8 * RGN + 1024];   // 109568 B -> 1 blk/CU
  const int bid = blockIdx.x;
  const int t = threadIdx.x, lane = t & 63, w = t >> 6;
  const int quad = lane >> 4, l15 = lane & 15;

  // ========== Phase 1: projections, stage-free quadrant wave-tasks ==========
  {
    const int gw = bid * 8 + w;
    if (gw < 1792) {
      int v = gw >> 2; const int qd = gw & 3;
      const float *A, *B, *bias; uint16_t* C; int mode;
      if (v < 64)       {           A = X;   B = wq;  bias = bq;  C = q;   mode = 2; }
      else if (v < 128) { v -= 64;  A = X;   B = wk;  bias = bk;  C = k;   mode = 2; }
      else if (v < 192) { v -= 128; A = X;   B = wv;  bias = bv;  C = vT;  mode = 3; }
      else if (v < 320) { v -= 192; A = emb; B = wrk; bias = brk; C = rkE; mode = 1; }
      else              { v -= 320; A = emb; B = wrq; bias = brq; C = rqE; mode = 1; }
      const int m0 = (v >> 3) * 64 + (qd & 1) * 32;
      const int n0 = (v & 7) * 64 + (qd >> 1) * 32;

      const float* Ab = A + (size_t)(m0 + l15) * 512 + quad * 8;
      const float* Bb = B + (size_t)(n0 + l15) * 512 + quad * 8;

      f32x4 acc[2][2] = {};
      for (int k0 = 0; k0 < 512; k0 += 32) {
        bf16x8 af[2], bfr[2];
#pragma unroll
        for (int x = 0; x < 2; x++) {
          const float* pa = Ab + (size_t)(x * 16) * 512 + k0;
          af[x] = cvt8f(*(const float4*)pa, *(const float4*)(pa + 4));
        }
#pragma unroll
        for (int y = 0; y < 2; y++) {
          const float* pb = Bb + (size_t)(y * 16) * 512 + k0;
          bfr[y] = cvt8f(*(const float4*)pb, *(const float4*)(pb + 4));
        }
#pragma unroll
        for (int x = 0; x < 2; x++)
#pragma unroll
          for (int y = 0; y < 2; y++)
            acc[x][y] = MFMA(af[x], bfr[y], acc[x][y]);
      }
#pragma unroll
      for (int x = 0; x < 2; x++)
#pragma unroll
        for (int y = 0; y < 2; y++) {
          const int j = n0 + y * 16 + l15;
          const float bval = bias[j];
          const int ib = m0 + x * 16 + quad * 4;
#pragma unroll
          for (int r = 0; r < 4; r++) {
            const int i = ib + r;
            size_t off;
            if (mode == 1)      off = (size_t)i * 512 + j;
            else if (mode == 2) off = (size_t)(j >> 6) * 32768 + (size_t)i * 64 + (size_t)(j & 63);
            else                off = (size_t)(j >> 6) * 32768 + (size_t)(j & 63) * 512 + (size_t)i;
            C[off] = f2bf(acc[x][y][r] + bval);
          }
        }
    }
  }
  grid_bar(flagsA);

  // ========== Phase 2: attn (scores + softmax + PV), R8/R9 body ==========
  {
    const int h = bid & 7, i0 = (bid >> 3) * 16;   // h == XCD id
    const int j0 = w * 64;
    const int ebase = j0 - i0 + 497;               // in [1, 945]

    char* rgn = smem + w * RGN;
    _Float16* U2h = (_Float16*)rgn;                // 16 x 84
    _Float16* U3h = (_Float16*)(rgn + 2688);       // 80 x 68
    uint16_t* Pw  = (uint16_t*)rgn;                // 16 x SSTR (PV phase)
    float*    ctxw = (float*)(rgn + 4096);         // 16 x 64   (epilogue)
    float* rmax = (float*)(smem + 8 * RGN);        // [8][16]
    float* rsum = rmax + 128;                      // [8][16]

    const uint16_t* qh = q  + (size_t)h * 32768;
    const uint16_t* kh = k  + (size_t)h * 32768;
    const uint16_t* vh = vT + (size_t)h * 32768;

    f32x4 acc1[4] = {}, acc2[5] = {}, acc3[5][4] = {};
#pragma unroll
    for (int s = 0; s < 2; s++) {
      const int ko = s * 32 + quad * 8;
      bf16x8 aq = *(const bf16x8*)(qh + (size_t)(i0 + l15) * 64 + ko);
      bf16x8 bk[4], arq[5], brk[5];
#pragma unroll
      for (int tt = 0; tt < 4; tt++)
        bk[tt] = *(const bf16x8*)(kh + (size_t)(j0 + tt * 16 + l15) * 64 + ko);
#pragma unroll
      for (int x = 0; x < 5; x++) {
        const int e = min(ebase + x * 16 + l15, 1023);
        arq[x] = *(const bf16x8*)(rqE + (size_t)e * 512 + h * 64 + ko);
        brk[x] = *(const bf16x8*)(rkE + (size_t)e * 512 + h * 64 + ko);
      }
#pragma unroll
      for (int tt = 0; tt < 4; tt++) acc1[tt] = MFMA(aq, bk[tt], acc1[tt]);
#pragma unroll
      for (int x = 0; x < 5; x++)    acc2[x] = MFMA(aq, brk[x], acc2[x]);
#pragma unroll
      for (int x = 0; x < 5; x++)
#pragma unroll
        for (int tt = 0; tt < 4; tt++) acc3[x][tt] = MFMA(arq[x], bk[tt], acc3[x][tt]);
    }
    // U round-trip (wave-private, fp16)
#pragma unroll
    for (int x = 0; x < 5; x++)
#pragma unroll
      for (int r = 0; r < 4; r++)
        U2h[(quad * 4 + r) * 84 + x * 16 + l15] = (_Float16)acc2[x][r];
#pragma unroll
    for (int x = 0; x < 5; x++)
#pragma unroll
      for (int tt = 0; tt < 4; tt++)
#pragma unroll
        for (int r = 0; r < 4; r++)
          U3h[(x * 16 + quad * 4 + r) * 68 + tt * 16 + l15] = (_Float16)acc3[x][tt][r];
    __syncthreads();

    f32x4 sc[4];
#pragma unroll
    for (int tt = 0; tt < 4; tt++)
#pragma unroll
      for (int r = 0; r < 4; r++) {
        const int ii = quad * 4 + r, jj = tt * 16 + l15;
        const int rb = jj - ii + 15;   // [0,78]
        sc[tt][r] = (acc1[tt][r] + (float)U2h[ii * 84 + rb] + (float)U3h[rb * 68 + jj]) * 0.125f;
      }

    // softmax over j=512 (8 waves share each row)
    float mrow[4];
#pragma unroll
    for (int r = 0; r < 4; r++) {
      float m = fmaxf(fmaxf(sc[0][r], sc[1][r]), fmaxf(sc[2][r], sc[3][r]));
#pragma unroll
      for (int o = 1; o < 16; o <<= 1) m = fmaxf(m, __shfl_xor(m, o, 64));
      mrow[r] = m;
    }
    if (l15 == 0)
#pragma unroll
      for (int r = 0; r < 4; r++) rmax[w * 16 + quad * 4 + r] = mrow[r];
    __syncthreads();
    float srow[4];
#pragma unroll
    for (int r = 0; r < 4; r++) {
      const int row = quad * 4 + r;
      float m = rmax[row];
#pragma unroll
      for (int x = 1; x < 8; x++) m = fmaxf(m, rmax[x * 16 + row]);
      float s = 0.f;
#pragma unroll
      for (int tt = 0; tt < 4; tt++) {
        const float p = __expf(sc[tt][r] - m);
        sc[tt][r] = p; s += p;
      }
#pragma unroll
      for (int o = 1; o < 16; o <<= 1) s += __shfl_xor(s, o, 64);
      srow[r] = s;
    }
    if (l15 == 0)
#pragma unroll
      for (int r = 0; r < 4; r++) rsum[w * 16 + quad * 4 + r] = srow[r];
    __syncthreads();
#pragma unroll
    for (int r = 0; r < 4; r++) {
      const int row = quad * 4 + r;
      float s = rsum[row];
#pragma unroll
      for (int x = 1; x < 8; x++) s += rsum[x * 16 + row];
      const float inv = 1.0f / s;
#pragma unroll
      for (int tt = 0; tt < 4; tt++) {
        sc[tt][r] *= inv;
        attn[((size_t)h * 512 + i0 + row) * 512 + j0 + tt * 16 + l15] = sc[tt][r];
      }
    }

    // PV: wave-partial ctx[16][64] over this wave's 64 j
#pragma unroll
    for (int tt = 0; tt < 4; tt++)
#pragma unroll
      for (int r = 0; r < 4; r++)
        Pw[(quad * 4 + r) * SSTR + tt * 16 + l15] = f2bf(sc[tt][r]);
    __syncthreads();
    f32x4 apv[4] = {};
#pragma unroll
    for (int s = 0; s < 2; s++) {
      const int ko = s * 32 + quad * 8;
      bf16x8 aP = *(const bf16x8*)(&Pw[l15 * SSTR + ko]);
#pragma unroll
      for (int tt = 0; tt < 4; tt++) {
        bf16x8 bv = *(const bf16x8*)(vh + (size_t)(tt * 16 + l15) * 512 + j0 + ko);
        apv[tt] = MFMA(aP, bv, apv[tt]);
      }
    }
#pragma unroll
    for (int tt = 0; tt < 4; tt++)
#pragma unroll
      for (int r = 0; r < 4; r++)
        ctxw[(quad * 4 + r) * 64 + tt * 16 + l15] = apv[tt][r];
    __syncthreads();
    // cross-wave ctx sum (512 thr x 2 floats) -> ctx_bf
    {
      const int idx = t * 2, row = idx >> 6, col = idx & 63;
      const size_t off = 4096 + (size_t)(row * 64 + col) * 4;
      float c0 = 0.f, c1 = 0.f;
#pragma unroll
      for (int x = 0; x < 8; x++) {
        float2 vv = *(const float2*)(smem + x * RGN + off);
        c0 += vv.x; c1 += vv.y;
      }
      *(uint32_t*)(ctx_bf + (size_t)(i0 + row) * 512 + h * 64 + col) = cvt2(c0, c1);
    }
  }
  grid_bar(flagsB);

  // ========== Phase 3: out = ctx * wo^T + bo, stage-free quadrants ==========
  {
    const int gw = bid * 8 + w;
    if (gw < 256) {
      const int v = gw >> 2, qd = gw & 3;
      const int m0 = (v >> 3) * 64 + (qd & 1) * 32;
      const int n0 = (v & 7) * 64 + (qd >> 1) * 32;

      const uint16_t* Ab = ctx_bf + (size_t)(m0 + l15) * 512 + quad * 8;
      const float* Bb = wo + (size_t)(n0 + l15) * 512 + quad * 8;

      f32x4 acc[2][2] = {};
      for (int k0 = 0; k0 < 512; k0 += 32) {
        bf16x8 af[2], bfr[2];
#pragma unroll
        for (int x = 0; x < 2; x++)
          af[x] = *(const bf16x8*)(Ab + (size_t)(x * 16) * 512 + k0);
#pragma unroll
        for (int y = 0; y < 2; y++) {
          const float* pb = Bb + (size_t)(y * 16) * 512 + k0;
          bfr[y] = cvt8f(*(const float4*)pb, *(const float4*)(pb + 4));
        }
#pragma unroll
        for (int x = 0; x < 2; x++)
#pragma unroll
          for (int y = 0; y < 2; y++)
            acc[x][y] = MFMA(af[x], bfr[y], acc[x][y]);
      }
#pragma unroll
      for (int x = 0; x < 2; x++)
#pragma unroll
        for (int y = 0; y < 2; y++) {
          const int j = n0 + y * 16 + l15;
          const float bval = bo[j];
          const int ib = m0 + x * 16 + quad * 4;
#pragma unroll
          for (int r = 0; r < 4; r++)
            outp[(size_t)(ib + r) * 512 + j] = acc[x][y][r] + bval;
        }
    }
  }
}

extern "C" void kernel_launch(void* const* d_in, const int* in_sizes, int n_in,
                              void* d_out, int out_size, void* d_ws, size_t ws_size,
                              hipStream_t stream) {
  const float* X   = (const float*)d_in[0];
  const float* emb = (const float*)d_in[1];
  const float* wq  = (const float*)d_in[2];
  const float* bq  = (const float*)d_in[3];
  const float* wk  = (const float*)d_in[4];
  const float* bk  = (const float*)d_in[5];
  const float* wv  = (const float*)d_in[6];
  const float* bv  = (const float*)d_in[7];
  const float* wrk = (const float*)d_in[8];
  const float* brk = (const float*)d_in[9];
  const float* wrq = (const float*)d_in[10];
  const float* brq = (const float*)d_in[11];
  const float* wo  = (const float*)d_in[12];
  const float* bo  = (const float*)d_in[13];

  // ws layout (uint16 elems, ~4.2 MB): tensors + two 256-int flag arrays
  uint16_t* q      = (uint16_t*)d_ws;         // [8][512][64]
  uint16_t* k      = q   + 262144;            // [8][512][64]
  uint16_t* vT     = k   + 262144;            // [8][64][512]
  uint16_t* rkE    = vT  + 262144;            // [1024][512]
  uint16_t* rqE    = rkE + 524288;            // [1024][512]
  uint16_t* ctx_bf = rqE + 524288;            // [512][512]
  int*      flagsA = (int*)(ctx_bf + 262144); // [256]
  int*      flagsB = flagsA + 256;            // [256]

  float* outp = (float*)d_out;                // [512][512]
  float* attn = (float*)d_out + 262144;       // [8][512][512]

  fused_kernel<<<dim3(NBLK), dim3(512), 0, stream>>>(
      X, emb, wq, bq, wk, bk, wv, bv, wrk, brk, wrq, brq, wo, bo,
      q, k, vT, rkE, rqE, ctx_bf, attn, outp, flagsA, flagsB);
}

// Round 13
// 239.501 us; speedup vs baseline: 1.2037x; 1.1706x over previous
//
#include <hip/hip_runtime.h>
#include <stdint.h>

// HeAttention, MI355X/gfx950 — Round 13: persistent kernel, RELAXED-poll
// grid barrier. R11/R12 post-mortem: acquire-per-poll atomic loads emit a
// buffer_inv (L2 invalidate) EACH — 256 blocks spinning = continuous L2
// invalidate storm that evicts working blocks' operands (feedback loop).
// Fix: poll with relaxed agent loads (sc1 visibility, no invalidate),
// s_sleep(32) pacing, rare acquire nudge as deadlock guard, ONE
// __threadfence after the barrier for data visibility.
//   Phase 1 proj: 448 tiles x 4 quadrants = 1792 stage-free wave-tasks.
//   Phase 2 attn: R8/R9 body (scores + softmax + PV), per-wave LDS regions.
//   Phase 3 out: 64 tiles x 4 quadrants = 256 stage-free wave-tasks.
// LDS 109.6 KB -> 1 block/CU; 256 blocks co-resident (validated R7/11/12).
// Flags in ws (0xAA-poisoned each launch => self-initializing; two arrays).
// fp32 I/O, bf16 MFMA internally. B=1, S=512, D=512, H=8, hd=64, NE=1024.

typedef __bf16 bf16_t;
typedef bf16_t bf16x8 __attribute__((ext_vector_type(8)));
typedef float f32x4 __attribute__((ext_vector_type(4)));
typedef float f32x2v __attribute__((ext_vector_type(2)));
typedef bf16_t bf16x2v __attribute__((ext_vector_type(2)));

__device__ __forceinline__ uint16_t f2bf(float f) {
  bf16_t b = (bf16_t)f;                       // compiler RNE (HW cvt)
  union { bf16_t b; uint16_t u; } c; c.b = b; return c.u;
}
__device__ __forceinline__ uint32_t cvt2(float lo, float hi) {
  bf16x2v v = __builtin_convertvector((f32x2v){lo, hi}, bf16x2v);
  union { bf16x2v v; uint32_t u; } c; c.v = v; return c.u;
}
__device__ __forceinline__ bf16x8 cvt8f(float4 a, float4 b) {
  uint4 r;
  r.x = cvt2(a.x, a.y); r.y = cvt2(a.z, a.w);
  r.z = cvt2(b.x, b.y); r.w = cvt2(b.z, b.w);
  union { uint4 u; bf16x8 v; } c; c.u = r; return c.v;
}
#define MFMA(a, b, c) __builtin_amdgcn_mfma_f32_16x16x32_bf16((a), (b), (c), 0, 0, 0)

#define SSTR 72     // P-tile stride (bf16)
#define RGN  13568  // attn per-wave LDS region bytes
#define NBLK 256

// Grid barrier: parallel per-block release stores; ONE wave scans with
// RELAXED agent loads (no per-load L2 invalidate!), sleep-paced, with a
// rare acquire nudge for guaranteed progress.
__device__ __forceinline__ void grid_bar(int* flags) {
  __syncthreads();
  if (threadIdx.x == 0) {
    __threadfence();  // release: publish this block's stores device-wide
    __hip_atomic_store(&flags[blockIdx.x], 1, __ATOMIC_RELEASE, __HIP_MEMORY_SCOPE_AGENT);
  }
  if (threadIdx.x < 64) {
    const int l = threadIdx.x;
    int spin = 0;
    bool done;
    do {
      bool ok = true;
#pragma unroll
      for (int c = 0; c < 4; c++)
        ok &= (__hip_atomic_load(&flags[c * 64 + l], __ATOMIC_RELAXED,
                                 __HIP_MEMORY_SCOPE_AGENT) == 1);
      done = __all(ok);
      if (!done) {
        __builtin_amdgcn_s_sleep(32);
        if (((++spin) & 15) == 0)   // deadlock guard: rare acquire
          (void)__hip_atomic_load(&flags[l], __ATOMIC_ACQUIRE, __HIP_MEMORY_SCOPE_AGENT);
      }
    } while (!done);
  }
  __syncthreads();
  __threadfence();  // single acquire-side invalidate before consuming data
}

__global__ __launch_bounds__(512, 2) void fused_kernel(
    const float* __restrict__ X, const float* __restrict__ emb,
    const float* __restrict__ wq, const float* __restrict__ bq,
    const float* __restrict__ wk, const float* __restrict__ bk,
    const float* __restrict__ wv, const float* __restrict__ bv,
    const float* __restrict__ wrk, const float* __restrict__ brk,
    const float* __restrict__ wrq, const float* __restrict__ brq,
    const float* __restrict__ wo, const float* __restrict__ bo,
    uint16_t* __restrict__ q, uint16_t* __restrict__ k, uint16_t* __restrict__ vT,
    uint16_t* __restrict__ rkE, uint16_t* __restrict__ rqE,
    uint16_t* __restrict__ ctx_bf, float* __restrict__ attn,
    float* __restrict__ outp, int* __restrict__ flagsA, int* __restrict__ flagsB)
{
  __shared__ __align__(16) char smem[8 * RGN + 1024];   // 109568 B -> 1 blk/CU
  const int bid = blockIdx.x;
  const int t = threadIdx.x, lane = t & 63, w = t >> 6;
  const int quad = lane >> 4, l15 = lane & 15;

  // ========== Phase 1: projections, stage-free quadrant wave-tasks ==========
  {
    const int gw = bid * 8 + w;
    if (gw < 1792) {
      int v = gw >> 2; const int qd = gw & 3;
      const float *A, *B, *bias; uint16_t* C; int mode;
      if (v < 64)       {           A = X;   B = wq;  bias = bq;  C = q;   mode = 2; }
      else if (v < 128) { v -= 64;  A = X;   B = wk;  bias = bk;  C = k;   mode = 2; }
      else if (v < 192) { v -= 128; A = X;   B = wv;  bias = bv;  C = vT;  mode = 3; }
      else if (v < 320) { v -= 192; A = emb; B = wrk; bias = brk; C = rkE; mode = 1; }
      else              { v -= 320; A = emb; B = wrq; bias = brq; C = rqE; mode = 1; }
      const int m0 = (v >> 3) * 64 + (qd & 1) * 32;
      const int n0 = (v & 7) * 64 + (qd >> 1) * 32;

      const float* Ab = A + (size_t)(m0 + l15) * 512 + quad * 8;
      const float* Bb = B + (size_t)(n0 + l15) * 512 + quad * 8;

      f32x4 acc[2][2] = {};
      for (int k0 = 0; k0 < 512; k0 += 32) {
        bf16x8 af[2], bfr[2];
#pragma unroll
        for (int x = 0; x < 2; x++) {
          const float* pa = Ab + (size_t)(x * 16) * 512 + k0;
          af[x] = cvt8f(*(const float4*)pa, *(const float4*)(pa + 4));
        }
#pragma unroll
        for (int y = 0; y < 2; y++) {
          const float* pb = Bb + (size_t)(y * 16) * 512 + k0;
          bfr[y] = cvt8f(*(const float4*)pb, *(const float4*)(pb + 4));
        }
#pragma unroll
        for (int x = 0; x < 2; x++)
#pragma unroll
          for (int y = 0; y < 2; y++)
            acc[x][y] = MFMA(af[x], bfr[y], acc[x][y]);
      }
#pragma unroll
      for (int x = 0; x < 2; x++)
#pragma unroll
        for (int y = 0; y < 2; y++) {
          const int j = n0 + y * 16 + l15;
          const float bval = bias[j];
          const int ib = m0 + x * 16 + quad * 4;
#pragma unroll
          for (int r = 0; r < 4; r++) {
            const int i = ib + r;
            size_t off;
            if (mode == 1)      off = (size_t)i * 512 + j;
            else if (mode == 2) off = (size_t)(j >> 6) * 32768 + (size_t)i * 64 + (size_t)(j & 63);
            else                off = (size_t)(j >> 6) * 32768 + (size_t)(j & 63) * 512 + (size_t)i;
            C[off] = f2bf(acc[x][y][r] + bval);
          }
        }
    }
  }
  grid_bar(flagsA);

  // ========== Phase 2: attn (scores + softmax + PV), R8/R9 body ==========
  {
    const int h = bid & 7, i0 = (bid >> 3) * 16;   // h == XCD id
    const int j0 = w * 64;
    const int ebase = j0 - i0 + 497;               // in [1, 945]

    char* rgn = smem + w * RGN;
    _Float16* U2h = (_Float16*)rgn;                // 16 x 84
    _Float16* U3h = (_Float16*)(rgn + 2688);       // 80 x 68
    uint16_t* Pw  = (uint16_t*)rgn;                // 16 x SSTR (PV phase)
    float*    ctxw = (float*)(rgn + 4096);         // 16 x 64   (epilogue)
    float* rmax = (float*)(smem + 8 * RGN);        // [8][16]
    float* rsum = rmax + 128;                      // [8][16]

    const uint16_t* qh = q  + (size_t)h * 32768;
    const uint16_t* kh = k  + (size_t)h * 32768;
    const uint16_t* vh = vT + (size_t)h * 32768;

    f32x4 acc1[4] = {}, acc2[5] = {}, acc3[5][4] = {};
#pragma unroll
    for (int s = 0; s < 2; s++) {
      const int ko = s * 32 + quad * 8;
      bf16x8 aq = *(const bf16x8*)(qh + (size_t)(i0 + l15) * 64 + ko);
      bf16x8 bk[4], arq[5], brk[5];
#pragma unroll
      for (int tt = 0; tt < 4; tt++)
        bk[tt] = *(const bf16x8*)(kh + (size_t)(j0 + tt * 16 + l15) * 64 + ko);
#pragma unroll
      for (int x = 0; x < 5; x++) {
        const int e = min(ebase + x * 16 + l15, 1023);
        arq[x] = *(const bf16x8*)(rqE + (size_t)e * 512 + h * 64 + ko);
        brk[x] = *(const bf16x8*)(rkE + (size_t)e * 512 + h * 64 + ko);
      }
#pragma unroll
      for (int tt = 0; tt < 4; tt++) acc1[tt] = MFMA(aq, bk[tt], acc1[tt]);
#pragma unroll
      for (int x = 0; x < 5; x++)    acc2[x] = MFMA(aq, brk[x], acc2[x]);
#pragma unroll
      for (int x = 0; x < 5; x++)
#pragma unroll
        for (int tt = 0; tt < 4; tt++) acc3[x][tt] = MFMA(arq[x], bk[tt], acc3[x][tt]);
    }
    // U round-trip (wave-private, fp16)
#pragma unroll
    for (int x = 0; x < 5; x++)
#pragma unroll
      for (int r = 0; r < 4; r++)
        U2h[(quad * 4 + r) * 84 + x * 16 + l15] = (_Float16)acc2[x][r];
#pragma unroll
    for (int x = 0; x < 5; x++)
#pragma unroll
      for (int tt = 0; tt < 4; tt++)
#pragma unroll
        for (int r = 0; r < 4; r++)
          U3h[(x * 16 + quad * 4 + r) * 68 + tt * 16 + l15] = (_Float16)acc3[x][tt][r];
    __syncthreads();

    f32x4 sc[4];
#pragma unroll
    for (int tt = 0; tt < 4; tt++)
#pragma unroll
      for (int r = 0; r < 4; r++) {
        const int ii = quad * 4 + r, jj = tt * 16 + l15;
        const int rb = jj - ii + 15;   // [0,78]
        sc[tt][r] = (acc1[tt][r] + (float)U2h[ii * 84 + rb] + (float)U3h[rb * 68 + jj]) * 0.125f;
      }

    // softmax over j=512 (8 waves share each row)
    float mrow[4];
#pragma unroll
    for (int r = 0; r < 4; r++) {
      float m = fmaxf(fmaxf(sc[0][r], sc[1][r]), fmaxf(sc[2][r], sc[3][r]));
#pragma unroll
      for (int o = 1; o < 16; o <<= 1) m = fmaxf(m, __shfl_xor(m, o, 64));
      mrow[r] = m;
    }
    if (l15 == 0)
#pragma unroll
      for (int r = 0; r < 4; r++) rmax[w * 16 + quad * 4 + r] = mrow[r];
    __syncthreads();
    float srow[4];
#pragma unroll
    for (int r = 0; r < 4; r++) {
      const int row = quad * 4 + r;
      float m = rmax[row];
#pragma unroll
      for (int x = 1; x < 8; x++) m = fmaxf(m, rmax[x * 16 + row]);
      float s = 0.f;
#pragma unroll
      for (int tt = 0; tt < 4; tt++) {
        const float p = __expf(sc[tt][r] - m);
        sc[tt][r] = p; s += p;
      }
#pragma unroll
      for (int o = 1; o < 16; o <<= 1) s += __shfl_xor(s, o, 64);
      srow[r] = s;
    }
    if (l15 == 0)
#pragma unroll
      for (int r = 0; r < 4; r++) rsum[w * 16 + quad * 4 + r] = srow[r];
    __syncthreads();
#pragma unroll
    for (int r = 0; r < 4; r++) {
      const int row = quad * 4 + r;
      float s = rsum[row];
#pragma unroll
      for (int x = 1; x < 8; x++) s += rsum[x * 16 + row];
      const float inv = 1.0f / s;
#pragma unroll
      for (int tt = 0; tt < 4; tt++) {
        sc[tt][r] *= inv;
        attn[((size_t)h * 512 + i0 + row) * 512 + j0 + tt * 16 + l15] = sc[tt][r];
      }
    }

    // PV: wave-partial ctx[16][64] over this wave's 64 j
#pragma unroll
    for (int tt = 0; tt < 4; tt++)
#pragma unroll
      for (int r = 0; r < 4; r++)
        Pw[(quad * 4 + r) * SSTR + tt * 16 + l15] = f2bf(sc[tt][r]);
    __syncthreads();
    f32x4 apv[4] = {};
#pragma unroll
    for (int s = 0; s < 2; s++) {
      const int ko = s * 32 + quad * 8;
      bf16x8 aP = *(const bf16x8*)(&Pw[l15 * SSTR + ko]);
#pragma unroll
      for (int tt = 0; tt < 4; tt++) {
        bf16x8 bv = *(const bf16x8*)(vh + (size_t)(tt * 16 + l15) * 512 + j0 + ko);
        apv[tt] = MFMA(aP, bv, apv[tt]);
      }
    }
#pragma unroll
    for (int tt = 0; tt < 4; tt++)
#pragma unroll
      for (int r = 0; r < 4; r++)
        ctxw[(quad * 4 + r) * 64 + tt * 16 + l15] = apv[tt][r];
    __syncthreads();
    // cross-wave ctx sum (512 thr x 2 floats) -> ctx_bf
    {
      const int idx = t * 2, row = idx >> 6, col = idx & 63;
      const size_t off = 4096 + (size_t)(row * 64 + col) * 4;
      float c0 = 0.f, c1 = 0.f;
#pragma unroll
      for (int x = 0; x < 8; x++) {
        float2 vv = *(const float2*)(smem + x * RGN + off);
        c0 += vv.x; c1 += vv.y;
      }
      *(uint32_t*)(ctx_bf + (size_t)(i0 + row) * 512 + h * 64 + col) = cvt2(c0, c1);
    }
  }
  grid_bar(flagsB);

  // ========== Phase 3: out = ctx * wo^T + bo, stage-free quadrants ==========
  {
    const int gw = bid * 8 + w;
    if (gw < 256) {
      const int v = gw >> 2, qd = gw & 3;
      const int m0 = (v >> 3) * 64 + (qd & 1) * 32;
      const int n0 = (v & 7) * 64 + (qd >> 1) * 32;

      const uint16_t* Ab = ctx_bf + (size_t)(m0 + l15) * 512 + quad * 8;
      const float* Bb = wo + (size_t)(n0 + l15) * 512 + quad * 8;

      f32x4 acc[2][2] = {};
      for (int k0 = 0; k0 < 512; k0 += 32) {
        bf16x8 af[2], bfr[2];
#pragma unroll
        for (int x = 0; x < 2; x++)
          af[x] = *(const bf16x8*)(Ab + (size_t)(x * 16) * 512 + k0);
#pragma unroll
        for (int y = 0; y < 2; y++) {
          const float* pb = Bb + (size_t)(y * 16) * 512 + k0;
          bfr[y] = cvt8f(*(const float4*)pb, *(const float4*)(pb + 4));
        }
#pragma unroll
        for (int x = 0; x < 2; x++)
#pragma unroll
          for (int y = 0; y < 2; y++)
            acc[x][y] = MFMA(af[x], bfr[y], acc[x][y]);
      }
#pragma unroll
      for (int x = 0; x < 2; x++)
#pragma unroll
        for (int y = 0; y < 2; y++) {
          const int j = n0 + y * 16 + l15;
          const float bval = bo[j];
          const int ib = m0 + x * 16 + quad * 4;
#pragma unroll
          for (int r = 0; r < 4; r++)
            outp[(size_t)(ib + r) * 512 + j] = acc[x][y][r] + bval;
        }
    }
  }
}

extern "C" void kernel_launch(void* const* d_in, const int* in_sizes, int n_in,
                              void* d_out, int out_size, void* d_ws, size_t ws_size,
                              hipStream_t stream) {
  const float* X   = (const float*)d_in[0];
  const float* emb = (const float*)d_in[1];
  const float* wq  = (const float*)d_in[2];
  const float* bq  = (const float*)d_in[3];
  const float* wk  = (const float*)d_in[4];
  const float* bk  = (const float*)d_in[5];
  const float* wv  = (const float*)d_in[6];
  const float* bv  = (const float*)d_in[7];
  const float* wrk = (const float*)d_in[8];
  const float* brk = (const float*)d_in[9];
  const float* wrq = (const float*)d_in[10];
  const float* brq = (const float*)d_in[11];
  const float* wo  = (const float*)d_in[12];
  const float* bo  = (const float*)d_in[13];

  // ws layout (uint16 elems, ~4.2 MB): tensors + two 256-int flag arrays
  uint16_t* q      = (uint16_t*)d_ws;         // [8][512][64]
  uint16_t* k      = q   + 262144;            // [8][512][64]
  uint16_t* vT     = k   + 262144;            // [8][64][512]
  uint16_t* rkE    = vT  + 262144;            // [1024][512]
  uint16_t* rqE    = rkE + 524288;            // [1024][512]
  uint16_t* ctx_bf = rqE + 524288;            // [512][512]
  int*      flagsA = (int*)(ctx_bf + 262144); // [256]
  int*      flagsB = flagsA + 256;            // [256]

  float* outp = (float*)d_out;                // [512][512]
  float* attn = (float*)d_out + 262144;       // [8][512][512]

  fused_kernel<<<dim3(NBLK), dim3(512), 0, stream>>>(
      X, emb, wq, bq, wk, bk, wv, bv, wrk, brk, wrq, brq, wo, bo,
      q, k, vT, rkE, rqE, ctx_bf, attn, outp, flagsA, flagsB);
}

// Round 14
// 139.611 us; speedup vs baseline: 2.0650x; 1.7155x over previous
//
#include <hip/hip_runtime.h>
#include <stdint.h>

// HeAttention, MI355X/gfx950 — Round 14: back to 3 launches (R9 structure),
// GEMMs upgraded to stage-free quadrant wave-tasks at high TLP.
//   L1 proj: 448 blocks x 256 thr; 4 waves/block each compute a 32x32
//      quadrant with fragments read DIRECTLY from global (fp32->packed cvt).
//      No LDS, no barriers, 1792 waves = 7/CU. (R10 failed this at 1.75
//      waves/CU; R11-13 proved the body inside the persistent kernel.)
//   L2 attn: 256 blocks x 512 thr (R8/R9 proven body).
//   L3 out: 128 blocks x 128 thr, same stage-free quadrant pattern.
// Persistent-kernel path abandoned: MI355X cross-XCD spin barriers cost
// ~50us each regardless of construction (R7/R11/R12/R13).
// fp32 I/O, bf16 MFMA internally. B=1, S=512, D=512, H=8, hd=64, NE=1024.

typedef __bf16 bf16_t;
typedef bf16_t bf16x8 __attribute__((ext_vector_type(8)));
typedef float f32x4 __attribute__((ext_vector_type(4)));
typedef float f32x2v __attribute__((ext_vector_type(2)));
typedef bf16_t bf16x2v __attribute__((ext_vector_type(2)));

__device__ __forceinline__ uint16_t f2bf(float f) {
  bf16_t b = (bf16_t)f;                       // compiler RNE (HW cvt)
  union { bf16_t b; uint16_t u; } c; c.b = b; return c.u;
}
__device__ __forceinline__ uint32_t cvt2(float lo, float hi) {
  bf16x2v v = __builtin_convertvector((f32x2v){lo, hi}, bf16x2v);
  union { bf16x2v v; uint32_t u; } c; c.v = v; return c.u;
}
__device__ __forceinline__ bf16x8 cvt8f(float4 a, float4 b) {
  uint4 r;
  r.x = cvt2(a.x, a.y); r.y = cvt2(a.z, a.w);
  r.z = cvt2(b.x, b.y); r.w = cvt2(b.z, b.w);
  union { uint4 u; bf16x8 v; } c; c.u = r; return c.v;
}
#define MFMA(a, b, c) __builtin_amdgcn_mfma_f32_16x16x32_bf16((a), (b), (c), 0, 0, 0)

#define SSTR 72     // P-tile stride (bf16)
#define RGN  13568  // attn per-wave LDS region bytes

// ---------------- proj: stage-free quadrant wave-tasks ----------------
// Block = one 64x64 tile of one projection; wave w owns quadrant w.
// Tiles: [0,64) X*wq->q(mode2) | [64,128) X*wk->k(2) | [128,192) X*wv->vT(3)
//        [192,320) emb*wrk->rkE(1) | [320,448) emb*wrq->rqE(1)
__global__ __launch_bounds__(256) void proj_kernel(
    const float* __restrict__ X, const float* __restrict__ emb,
    const float* __restrict__ wq, const float* __restrict__ bq,
    const float* __restrict__ wk, const float* __restrict__ bk,
    const float* __restrict__ wv, const float* __restrict__ bv,
    const float* __restrict__ wrk, const float* __restrict__ brk,
    const float* __restrict__ wrq, const float* __restrict__ brq,
    uint16_t* __restrict__ q, uint16_t* __restrict__ k, uint16_t* __restrict__ vT,
    uint16_t* __restrict__ rkE, uint16_t* __restrict__ rqE)
{
  int v = blockIdx.x;
  const float *A, *B, *bias; uint16_t* C; int mode;
  if (v < 64)       {           A = X;   B = wq;  bias = bq;  C = q;   mode = 2; }
  else if (v < 128) { v -= 64;  A = X;   B = wk;  bias = bk;  C = k;   mode = 2; }
  else if (v < 192) { v -= 128; A = X;   B = wv;  bias = bv;  C = vT;  mode = 3; }
  else if (v < 320) { v -= 192; A = emb; B = wrk; bias = brk; C = rkE; mode = 1; }
  else              { v -= 320; A = emb; B = wrq; bias = brq; C = rqE; mode = 1; }

  const int t = threadIdx.x, lane = t & 63, w = t >> 6;   // w = quadrant
  const int quad = lane >> 4, l15 = lane & 15;
  const int m0 = (v >> 3) * 64 + (w & 1) * 32;
  const int n0 = (v & 7) * 64 + (w >> 1) * 32;

  const float* Ab = A + (size_t)(m0 + l15) * 512 + quad * 8;
  const float* Bb = B + (size_t)(n0 + l15) * 512 + quad * 8;

  f32x4 acc[2][2] = {};
  for (int k0 = 0; k0 < 512; k0 += 32) {
    bf16x8 af[2], bfr[2];
#pragma unroll
    for (int x = 0; x < 2; x++) {
      const float* pa = Ab + (size_t)(x * 16) * 512 + k0;
      af[x] = cvt8f(*(const float4*)pa, *(const float4*)(pa + 4));
    }
#pragma unroll
    for (int y = 0; y < 2; y++) {
      const float* pb = Bb + (size_t)(y * 16) * 512 + k0;
      bfr[y] = cvt8f(*(const float4*)pb, *(const float4*)(pb + 4));
    }
#pragma unroll
    for (int x = 0; x < 2; x++)
#pragma unroll
      for (int y = 0; y < 2; y++)
        acc[x][y] = MFMA(af[x], bfr[y], acc[x][y]);
  }
#pragma unroll
  for (int x = 0; x < 2; x++)
#pragma unroll
    for (int y = 0; y < 2; y++) {
      const int j = n0 + y * 16 + l15;
      const float bval = bias[j];
      const int ib = m0 + x * 16 + quad * 4;
#pragma unroll
      for (int r = 0; r < 4; r++) {
        const int i = ib + r;
        size_t off;
        if (mode == 1)      off = (size_t)i * 512 + j;
        else if (mode == 2) off = (size_t)(j >> 6) * 32768 + (size_t)i * 64 + (size_t)(j & 63);
        else                off = (size_t)(j >> 6) * 32768 + (size_t)(j & 63) * 512 + (size_t)i;
        C[off] = f2bf(acc[x][y][r] + bval);
      }
    }
}

// ---------------- attn: scores + softmax + PV, stage-free (R8/R9) ----------------
// Block (i-strip 16 rows, h); wave w of 8 owns j-tile j0 = w*64.
// Per-wave LDS region: U2h fp16 16x84 @+0 | U3h fp16 80x68 @+2688 |
// P bf16 16xSSTR @+0 (PV) | ctx partial f32 16x64 @+4096. Tail: rmax/rsum.
// score(ii,jj) = S1 + U2[ii,rb] + U3[rb,jj], rb = jj-ii+15 in [0,78];
// band base e = j0-i0+497 in [1,945] (clamped garbage row 79 never read).
__global__ __launch_bounds__(512, 2) void attn_kernel(
    const uint16_t* __restrict__ q, const uint16_t* __restrict__ k,
    const uint16_t* __restrict__ rkE, const uint16_t* __restrict__ rqE,
    const uint16_t* __restrict__ vT,
    float* __restrict__ attn, uint16_t* __restrict__ ctx_bf)
{
  __shared__ __align__(16) char smem[8 * RGN + 1024];
  const int h = blockIdx.y, i0 = blockIdx.x * 16;
  const int t = threadIdx.x, lane = t & 63, w = t >> 6;
  const int quad = lane >> 4, l15 = lane & 15;
  const int j0 = w * 64;
  const int ebase = j0 - i0 + 497;

  char* rgn = smem + w * RGN;
  _Float16* U2h = (_Float16*)rgn;              // 16 x 84
  _Float16* U3h = (_Float16*)(rgn + 2688);     // 80 x 68
  uint16_t* Pw  = (uint16_t*)rgn;              // 16 x SSTR (PV phase)
  float*    ctxw = (float*)(rgn + 4096);       // 16 x 64   (epilogue)
  float* rmax = (float*)(smem + 8 * RGN);      // [8][16]
  float* rsum = rmax + 128;                    // [8][16]

  const uint16_t* qh = q  + (size_t)h * 32768;
  const uint16_t* kh = k  + (size_t)h * 32768;
  const uint16_t* vh = vT + (size_t)h * 32768;

  f32x4 acc1[4] = {}, acc2[5] = {}, acc3[5][4] = {};
#pragma unroll
  for (int s = 0; s < 2; s++) {
    const int ko = s * 32 + quad * 8;
    bf16x8 aq = *(const bf16x8*)(qh + (size_t)(i0 + l15) * 64 + ko);
    bf16x8 bk[4], arq[5], brk[5];
#pragma unroll
    for (int tt = 0; tt < 4; tt++)
      bk[tt] = *(const bf16x8*)(kh + (size_t)(j0 + tt * 16 + l15) * 64 + ko);
#pragma unroll
    for (int x = 0; x < 5; x++) {
      const int e = min(ebase + x * 16 + l15, 1023);
      arq[x] = *(const bf16x8*)(rqE + (size_t)e * 512 + h * 64 + ko);
      brk[x] = *(const bf16x8*)(rkE + (size_t)e * 512 + h * 64 + ko);
    }
#pragma unroll
    for (int tt = 0; tt < 4; tt++) acc1[tt] = MFMA(aq, bk[tt], acc1[tt]);
#pragma unroll
    for (int x = 0; x < 5; x++)    acc2[x] = MFMA(aq, brk[x], acc2[x]);
#pragma unroll
    for (int x = 0; x < 5; x++)
#pragma unroll
      for (int tt = 0; tt < 4; tt++) acc3[x][tt] = MFMA(arq[x], bk[tt], acc3[x][tt]);
  }
  // U round-trip (wave-private, fp16)
#pragma unroll
  for (int x = 0; x < 5; x++)
#pragma unroll
    for (int r = 0; r < 4; r++)
      U2h[(quad * 4 + r) * 84 + x * 16 + l15] = (_Float16)acc2[x][r];
#pragma unroll
  for (int x = 0; x < 5; x++)
#pragma unroll
    for (int tt = 0; tt < 4; tt++)
#pragma unroll
      for (int r = 0; r < 4; r++)
        U3h[(x * 16 + quad * 4 + r) * 68 + tt * 16 + l15] = (_Float16)acc3[x][tt][r];
  __syncthreads();  // #1

  f32x4 sc[4];
#pragma unroll
  for (int tt = 0; tt < 4; tt++)
#pragma unroll
    for (int r = 0; r < 4; r++) {
      const int ii = quad * 4 + r, jj = tt * 16 + l15;
      const int rb = jj - ii + 15;   // [0,78]
      sc[tt][r] = (acc1[tt][r] + (float)U2h[ii * 84 + rb] + (float)U3h[rb * 68 + jj]) * 0.125f;
    }

  // softmax over j=512 (8 waves share each row)
  float mrow[4];
#pragma unroll
  for (int r = 0; r < 4; r++) {
    float m = fmaxf(fmaxf(sc[0][r], sc[1][r]), fmaxf(sc[2][r], sc[3][r]));
#pragma unroll
    for (int o = 1; o < 16; o <<= 1) m = fmaxf(m, __shfl_xor(m, o, 64));
    mrow[r] = m;
  }
  if (l15 == 0)
#pragma unroll
    for (int r = 0; r < 4; r++) rmax[w * 16 + quad * 4 + r] = mrow[r];
  __syncthreads();  // #2
  float srow[4];
#pragma unroll
  for (int r = 0; r < 4; r++) {
    const int row = quad * 4 + r;
    float m = rmax[row];
#pragma unroll
    for (int x = 1; x < 8; x++) m = fmaxf(m, rmax[x * 16 + row]);
    float s = 0.f;
#pragma unroll
    for (int tt = 0; tt < 4; tt++) {
      const float p = __expf(sc[tt][r] - m);
      sc[tt][r] = p; s += p;
    }
#pragma unroll
    for (int o = 1; o < 16; o <<= 1) s += __shfl_xor(s, o, 64);
    srow[r] = s;
  }
  if (l15 == 0)
#pragma unroll
    for (int r = 0; r < 4; r++) rsum[w * 16 + quad * 4 + r] = srow[r];
  __syncthreads();  // #3
#pragma unroll
  for (int r = 0; r < 4; r++) {
    const int row = quad * 4 + r;
    float s = rsum[row];
#pragma unroll
    for (int x = 1; x < 8; x++) s += rsum[x * 16 + row];
    const float inv = 1.0f / s;
#pragma unroll
    for (int tt = 0; tt < 4; tt++) {
      sc[tt][r] *= inv;
      attn[((size_t)h * 512 + i0 + row) * 512 + j0 + tt * 16 + l15] = sc[tt][r];
    }
  }

  // PV: wave-partial ctx[16][64] over this wave's 64 j
#pragma unroll
  for (int tt = 0; tt < 4; tt++)
#pragma unroll
    for (int r = 0; r < 4; r++)
      Pw[(quad * 4 + r) * SSTR + tt * 16 + l15] = f2bf(sc[tt][r]);
  __syncthreads();  // #4
  f32x4 apv[4] = {};
#pragma unroll
  for (int s = 0; s < 2; s++) {
    const int ko = s * 32 + quad * 8;
    bf16x8 aP = *(const bf16x8*)(&Pw[l15 * SSTR + ko]);
#pragma unroll
    for (int tt = 0; tt < 4; tt++) {
      bf16x8 bv = *(const bf16x8*)(vh + (size_t)(tt * 16 + l15) * 512 + j0 + ko);
      apv[tt] = MFMA(aP, bv, apv[tt]);
    }
  }
#pragma unroll
  for (int tt = 0; tt < 4; tt++)
#pragma unroll
    for (int r = 0; r < 4; r++)
      ctxw[(quad * 4 + r) * 64 + tt * 16 + l15] = apv[tt][r];
  __syncthreads();  // #5
  // cross-wave ctx sum (512 thr x 2 floats) -> ctx_bf
  {
    const int idx = t * 2, row = idx >> 6, col = idx & 63;
    const size_t off = 4096 + (size_t)(row * 64 + col) * 4;
    float c0 = 0.f, c1 = 0.f;
#pragma unroll
    for (int x = 0; x < 8; x++) {
      float2 vv = *(const float2*)(smem + x * RGN + off);
      c0 += vv.x; c1 += vv.y;
    }
    *(uint32_t*)(ctx_bf + (size_t)(i0 + row) * 512 + h * 64 + col) = cvt2(c0, c1);
  }
}

// ---------------- out: stage-free quadrant wave-tasks ----------------
// 64 tiles x 4 quadrants = 256 wave-tasks over 128 blocks x 2 waves.
__global__ __launch_bounds__(128) void out_kernel(
    const uint16_t* __restrict__ ctx_bf, const float* __restrict__ wo,
    const float* __restrict__ bo, float* __restrict__ outp)
{
  const int t = threadIdx.x, lane = t & 63, w = t >> 6;  // w in {0,1}
  const int quad = lane >> 4, l15 = lane & 15;
  const int v = blockIdx.x >> 1;                 // tile
  const int qd = (blockIdx.x & 1) * 2 + w;       // quadrant
  const int m0 = (v >> 3) * 64 + (qd & 1) * 32;
  const int n0 = (v & 7) * 64 + (qd >> 1) * 32;

  const uint16_t* Ab = ctx_bf + (size_t)(m0 + l15) * 512 + quad * 8;
  const float* Bb = wo + (size_t)(n0 + l15) * 512 + quad * 8;

  f32x4 acc[2][2] = {};
  for (int k0 = 0; k0 < 512; k0 += 32) {
    bf16x8 af[2], bfr[2];
#pragma unroll
    for (int x = 0; x < 2; x++)
      af[x] = *(const bf16x8*)(Ab + (size_t)(x * 16) * 512 + k0);
#pragma unroll
    for (int y = 0; y < 2; y++) {
      const float* pb = Bb + (size_t)(y * 16) * 512 + k0;
      bfr[y] = cvt8f(*(const float4*)pb, *(const float4*)(pb + 4));
    }
#pragma unroll
    for (int x = 0; x < 2; x++)
#pragma unroll
      for (int y = 0; y < 2; y++)
        acc[x][y] = MFMA(af[x], bfr[y], acc[x][y]);
  }
#pragma unroll
  for (int x = 0; x < 2; x++)
#pragma unroll
    for (int y = 0; y < 2; y++) {
      const int j = n0 + y * 16 + l15;
      const float bval = bo[j];
      const int ib = m0 + x * 16 + quad * 4;
#pragma unroll
      for (int r = 0; r < 4; r++)
        outp[(size_t)(ib + r) * 512 + j] = acc[x][y][r] + bval;
    }
}

extern "C" void kernel_launch(void* const* d_in, const int* in_sizes, int n_in,
                              void* d_out, int out_size, void* d_ws, size_t ws_size,
                              hipStream_t stream) {
  const float* X   = (const float*)d_in[0];
  const float* emb = (const float*)d_in[1];
  const float* wq  = (const float*)d_in[2];
  const float* bq  = (const float*)d_in[3];
  const float* wk  = (const float*)d_in[4];
  const float* bk  = (const float*)d_in[5];
  const float* wv  = (const float*)d_in[6];
  const float* bv  = (const float*)d_in[7];
  const float* wrk = (const float*)d_in[8];
  const float* brk = (const float*)d_in[9];
  const float* wrq = (const float*)d_in[10];
  const float* brq = (const float*)d_in[11];
  const float* wo  = (const float*)d_in[12];
  const float* bo  = (const float*)d_in[13];

  // ws layout (uint16 elems, ~4.2 MB):
  uint16_t* q      = (uint16_t*)d_ws;         // [8][512][64]
  uint16_t* k      = q   + 262144;            // [8][512][64]
  uint16_t* vT     = k   + 262144;            // [8][64][512]
  uint16_t* rkE    = vT  + 262144;            // [1024][512]
  uint16_t* rqE    = rkE + 524288;            // [1024][512]
  uint16_t* ctx_bf = rqE + 524288;            // [512][512]

  float* outp = (float*)d_out;                // [512][512]
  float* attn = (float*)d_out + 262144;       // [8][512][512]

  proj_kernel<<<dim3(448), dim3(256), 0, stream>>>(X, emb, wq, bq, wk, bk, wv, bv,
                                                   wrk, brk, wrq, brq, q, k, vT, rkE, rqE);
  attn_kernel<<<dim3(32, 8), dim3(512), 0, stream>>>(q, k, rkE, rqE, vT, attn, ctx_bf);
  out_kernel<<<dim3(128), dim3(128), 0, stream>>>(ctx_bf, wo, bo, outp);
}